// Round 1
// baseline (648.223 us; speedup 1.0000x reference)
//
#include <hip/hip_runtime.h>
#include <math.h>

#define B_N 2048
#define L_N 64
#define D_N 256   // EMBED_DIM
#define U_N 512   // UNITS

__device__ __forceinline__ float fast_tanh(float x) {
    // tanh(x) = 1 - 2/(e^{2x}+1); exact limits at +/-inf, fine vs 2% tolerance
    float e = __expf(2.0f * x);
    return 1.0f - 2.0f / (e + 1.0f);
}

// ---------------------------------------------------------------------------
// K1: ph[b][u] = hidden[b,:] . W2[:,u] + b1[u] + b2[u]
// grid (B/32, U/128) = (64,4), 256 threads, Kc=64, micro-tile 2b x 8u
// ---------------------------------------------------------------------------
__global__ __launch_bounds__(256) void proj_h_kernel(
    const float* __restrict__ hidden, const float* __restrict__ W2,
    const float* __restrict__ b1, const float* __restrict__ b2,
    float* __restrict__ ph)
{
    __shared__ float hs[32 * 68];    // [b][k], stride 68 (pad: banks + f4 align)
    __shared__ float w2s[64 * 128];  // [k][u]

    const int t  = threadIdx.x;
    const int b0 = blockIdx.x * 32;
    const int u0 = blockIdx.y * 128;
    const int ug = t & 15;   // 8 u's
    const int bg = t >> 4;   // 2 b's

    float acc[2][8];
#pragma unroll
    for (int i = 0; i < 2; ++i)
#pragma unroll
        for (int j = 0; j < 8; ++j) acc[i][j] = 0.f;

    for (int kc = 0; kc < 8; ++kc) {
        __syncthreads();
        // stage hidden tile 32x64 (512 float4, 2/thread)
#pragma unroll
        for (int i = 0; i < 2; ++i) {
            int f4 = t + i * 256;
            int bb = f4 >> 4;
            int kq = (f4 & 15) << 2;
            *(float4*)&hs[bb * 68 + kq] =
                *(const float4*)&hidden[(b0 + bb) * U_N + kc * 64 + kq];
        }
        // stage W2 tile 64x128 (2048 float4, 8/thread)
#pragma unroll
        for (int i = 0; i < 8; ++i) {
            int f4 = t + i * 256;
            int kk = f4 >> 5;
            int uq = (f4 & 31) << 2;
            *(float4*)&w2s[kk * 128 + uq] =
                *(const float4*)&W2[(kc * 64 + kk) * U_N + u0 + uq];
        }
        __syncthreads();

        for (int k = 0; k < 64; k += 4) {
            float4 a0 = *(const float4*)&hs[(bg * 2 + 0) * 68 + k];
            float4 a1 = *(const float4*)&hs[(bg * 2 + 1) * 68 + k];
            const float* ap0 = (const float*)&a0;
            const float* ap1 = (const float*)&a1;
#pragma unroll
            for (int kk = 0; kk < 4; ++kk) {
                float4 w0 = *(const float4*)&w2s[(k + kk) * 128 + ug * 8];
                float4 w1 = *(const float4*)&w2s[(k + kk) * 128 + ug * 8 + 4];
                float wv[8] = {w0.x, w0.y, w0.z, w0.w, w1.x, w1.y, w1.z, w1.w};
                float av0 = ap0[kk];
                float av1 = ap1[kk];
#pragma unroll
                for (int j = 0; j < 8; ++j) {
                    acc[0][j] = fmaf(av0, wv[j], acc[0][j]);
                    acc[1][j] = fmaf(av1, wv[j], acc[1][j]);
                }
            }
        }
    }

    // epilogue: += b1 + b2, store
    const int u = u0 + ug * 8;
    float4 b1a = *(const float4*)&b1[u];
    float4 b1b = *(const float4*)&b1[u + 4];
    float4 b2a = *(const float4*)&b2[u];
    float4 b2b = *(const float4*)&b2[u + 4];
    float bias[8] = {b1a.x + b2a.x, b1a.y + b2a.y, b1a.z + b2a.z, b1a.w + b2a.w,
                     b1b.x + b2b.x, b1b.y + b2b.y, b1b.z + b2b.z, b1b.w + b2b.w};
#pragma unroll
    for (int i = 0; i < 2; ++i) {
        int row = b0 + bg * 2 + i;
        float4 o0, o1;
        o0.x = acc[i][0] + bias[0]; o0.y = acc[i][1] + bias[1];
        o0.z = acc[i][2] + bias[2]; o0.w = acc[i][3] + bias[3];
        o1.x = acc[i][4] + bias[4]; o1.y = acc[i][5] + bias[5];
        o1.z = acc[i][6] + bias[6]; o1.w = acc[i][7] + bias[7];
        *(float4*)&ph[row * U_N + u]     = o0;
        *(float4*)&ph[row * U_N + u + 4] = o1;
    }
}

// ---------------------------------------------------------------------------
// K2: per-batch fused attention.
//  score = tanh(features[b] @ W1 + ph[b])      [64, 512]   (never materialized)
//  logits = score @ V + bV                     [64]
//  w = softmax_L(logits); ctx = sum_l w_l * features[b,l,:]
// grid 2048 blocks x 256 threads. micro-tile 4l x 8u, Uc=128, Kc=64.
// LDS: 17408 + 32768 + 4096 + 256 = 54528 B -> 2 blocks/CU
// ---------------------------------------------------------------------------
__global__ __launch_bounds__(256) void attn_kernel(
    const float* __restrict__ features, const float* __restrict__ W1,
    const float* __restrict__ V, const float* __restrict__ bV,
    const float* __restrict__ ph, float* __restrict__ out)
{
    __shared__ float fs[64 * 68];     // [l][k] chunk, stride 68
    __shared__ float w1s[64 * 128];   // [k][u] chunk
    __shared__ float lpart[16 * 64];  // [ug][l] logit partials
    __shared__ float wls[64];         // softmax weights

    const int b  = blockIdx.x;
    const int t  = threadIdx.x;
    const int ug = t & 15;   // 8 u's
    const int lg = t >> 4;   // 4 l's
    const float* fb = features + (size_t)b * (L_N * D_N);

    float lacc[4] = {0.f, 0.f, 0.f, 0.f};

    for (int uc = 0; uc < 4; ++uc) {
        float acc[4][8];
#pragma unroll
        for (int i = 0; i < 4; ++i)
#pragma unroll
            for (int j = 0; j < 8; ++j) acc[i][j] = 0.f;

        for (int kc = 0; kc < 4; ++kc) {
            __syncthreads();
            // stage features tile 64l x 64k (1024 float4, 4/thread)
#pragma unroll
            for (int i = 0; i < 4; ++i) {
                int f4 = t + i * 256;
                int l  = f4 >> 4;
                int kq = (f4 & 15) << 2;
                *(float4*)&fs[l * 68 + kq] =
                    *(const float4*)&fb[l * D_N + kc * 64 + kq];
            }
            // stage W1 tile 64k x 128u (2048 float4, 8/thread)
#pragma unroll
            for (int i = 0; i < 8; ++i) {
                int f4 = t + i * 256;
                int kk = f4 >> 5;
                int uq = (f4 & 31) << 2;
                *(float4*)&w1s[kk * 128 + uq] =
                    *(const float4*)&W1[(kc * 64 + kk) * U_N + uc * 128 + uq];
            }
            __syncthreads();

            for (int k = 0; k < 64; k += 4) {
                float4 a[4];
#pragma unroll
                for (int i = 0; i < 4; ++i)
                    a[i] = *(const float4*)&fs[(lg * 4 + i) * 68 + k];
#pragma unroll
                for (int kk = 0; kk < 4; ++kk) {
                    float4 w0 = *(const float4*)&w1s[(k + kk) * 128 + ug * 8];
                    float4 w1 = *(const float4*)&w1s[(k + kk) * 128 + ug * 8 + 4];
                    float wv[8] = {w0.x, w0.y, w0.z, w0.w, w1.x, w1.y, w1.z, w1.w};
#pragma unroll
                    for (int i = 0; i < 4; ++i) {
                        float av = ((const float*)&a[i])[kk];
#pragma unroll
                        for (int j = 0; j < 8; ++j)
                            acc[i][j] = fmaf(av, wv[j], acc[i][j]);
                    }
                }
            }
        }

        // epilogue for this u-chunk: tanh(acc + ph) . V  -> logit partials
        const float* phb = ph + (size_t)b * U_N + uc * 128 + ug * 8;
        float4 p0 = *(const float4*)&phb[0];
        float4 p1 = *(const float4*)&phb[4];
        const float* Vb = V + uc * 128 + ug * 8;
        float4 v0 = *(const float4*)&Vb[0];
        float4 v1 = *(const float4*)&Vb[4];
        float pv[8] = {p0.x, p0.y, p0.z, p0.w, p1.x, p1.y, p1.z, p1.w};
        float vv[8] = {v0.x, v0.y, v0.z, v0.w, v1.x, v1.y, v1.z, v1.w};
#pragma unroll
        for (int i = 0; i < 4; ++i)
#pragma unroll
            for (int j = 0; j < 8; ++j) {
                float s = fast_tanh(acc[i][j] + pv[j]);
                lacc[i] = fmaf(s, vv[j], lacc[i]);
            }
    }

    __syncthreads();
#pragma unroll
    for (int i = 0; i < 4; ++i)
        lpart[ug * 64 + lg * 4 + i] = lacc[i];
    __syncthreads();

    if (t < 64) {
        float lsum = bV[0];
#pragma unroll
        for (int g = 0; g < 16; ++g) lsum += lpart[g * 64 + t];
        // wave64 softmax over L
        float m = lsum;
#pragma unroll
        for (int off = 32; off > 0; off >>= 1)
            m = fmaxf(m, __shfl_xor(m, off));
        float e = __expf(lsum - m);
        float ssum = e;
#pragma unroll
        for (int off = 32; off > 0; off >>= 1)
            ssum += __shfl_xor(ssum, off);
        float w = e / ssum;
        wls[t] = w;
        out[B_N * D_N + b * L_N + t] = w;   // attention_weights [B, L, 1]
    }
    __syncthreads();

    // context[d] = sum_l w_l * features[b,l,d]  (features L2-hot, coalesced)
    float ctx = 0.f;
    for (int l = 0; l < 64; ++l)
        ctx = fmaf(wls[l], fb[l * D_N + t], ctx);
    out[b * D_N + t] = ctx;                 // context_vector [B, D]
}

// ---------------------------------------------------------------------------
extern "C" void kernel_launch(void* const* d_in, const int* in_sizes, int n_in,
                              void* d_out, int out_size, void* d_ws, size_t ws_size,
                              hipStream_t stream) {
    const float* features = (const float*)d_in[0];  // [2048, 64, 256]
    const float* hidden   = (const float*)d_in[1];  // [2048, 512]
    const float* W1       = (const float*)d_in[2];  // [256, 512]
    const float* b1       = (const float*)d_in[3];  // [512]
    const float* W2       = (const float*)d_in[4];  // [512, 512]
    const float* b2       = (const float*)d_in[5];  // [512]
    const float* V        = (const float*)d_in[6];  // [512, 1]
    const float* bV       = (const float*)d_in[7];  // [1]
    float* out = (float*)d_out;                     // ctx (524288) ++ attn (131072)
    float* ph  = (float*)d_ws;                      // [2048, 512] = 4 MB scratch

    dim3 g1(B_N / 32, U_N / 128);
    proj_h_kernel<<<g1, 256, 0, stream>>>(hidden, W2, b1, b2, ph);
    attn_kernel<<<B_N, 256, 0, stream>>>(features, W1, V, bV, ph, out);
}

// Round 2
// 307.401 us; speedup vs baseline: 2.1087x; 2.1087x over previous
//
#include <hip/hip_runtime.h>
#include <math.h>

#define B_N 2048
#define L_N 64
#define D_N 256   // EMBED_DIM
#define U_N 512   // UNITS

typedef __attribute__((ext_vector_type(8))) short bf16x8;   // 8 bf16 = 4 VGPRs
typedef __attribute__((ext_vector_type(4))) float f32x4;    // MFMA 16x16 acc

__device__ __forceinline__ float fast_tanh(float x) {
    float e = __expf(2.0f * x);
    return 1.0f - 2.0f / (e + 1.0f);
}
// fp32 -> bf16 round-to-nearest-even (dependency-free)
__device__ __forceinline__ ushort f2bf(float x) {
    uint b = __float_as_uint(x);
    uint r = (b + 0x7FFF + ((b >> 16) & 1)) >> 16;
    return (ushort)r;
}
__device__ __forceinline__ float bf2f(ushort u) {
    uint v = ((uint)u) << 16;
    return __uint_as_float(v);
}

// ---------------------------------------------------------------------------
// K0: pack W1 [256,512] fp32 -> bf16 in MFMA B-fragment order.
// chunk g = (ntg*8 + ks)*64 + lane holds W1[ks*32 + (lane>>4)*8 + j][ntg*16 + (lane&15)]
// for j=0..7 (16 B contiguous). 16384 chunks -> 64 blocks x 256 thr.
// ---------------------------------------------------------------------------
__global__ __launch_bounds__(256) void pack_w1(const float* __restrict__ W1,
                                               ushort* __restrict__ W1p) {
    int g = blockIdx.x * 256 + threadIdx.x;      // 0..16383
    int ntg  = g >> 9;
    int ks   = (g >> 6) & 7;
    int lane = g & 63;
    int n  = ntg * 16 + (lane & 15);
    int kb = ks * 32 + (lane >> 4) * 8;
    ushort tmp[8];
#pragma unroll
    for (int j = 0; j < 8; ++j) tmp[j] = f2bf(W1[(kb + j) * U_N + n]);
    *(uint4*)&W1p[(size_t)g * 8] = *(uint4*)tmp;
}

// ---------------------------------------------------------------------------
// K1: ph[b][u] = hidden[b,:] . W2[:,u] + b1[u] + b2[u]  (fp32 math, bf16 store)
// grid (B/8, U/128) = (256,4) = 1024 blocks (~3/CU), 256 thr, micro 1b x 4u
// ---------------------------------------------------------------------------
__global__ __launch_bounds__(256) void proj_h_kernel(
    const float* __restrict__ hidden, const float* __restrict__ W2,
    const float* __restrict__ b1, const float* __restrict__ b2,
    ushort* __restrict__ ph)
{
    __shared__ float hs[8 * 512];     // 16 KB, staged once
    __shared__ float w2s[64 * 128];   // 32 KB, per k-chunk

    const int t  = threadIdx.x;
    const int b0 = blockIdx.x * 8;
    const int u0 = blockIdx.y * 128;
    const int ug = t & 31;            // u = u0 + ug*4
    const int bg = t >> 5;            // b = b0 + bg

    // stage hidden 8x512 (1024 float4, 4/thread)
#pragma unroll
    for (int i = 0; i < 4; ++i) {
        int f4 = t + i * 256;
        *(float4*)&hs[(f4 >> 7) * 512 + (f4 & 127) * 4] =
            *(const float4*)&hidden[(b0 + (f4 >> 7)) * U_N + (f4 & 127) * 4];
    }

    float acc[4] = {0.f, 0.f, 0.f, 0.f};
    for (int kc = 0; kc < 8; ++kc) {
        __syncthreads();
        // stage W2 chunk 64k x 128u (2048 float4, 8/thread)
#pragma unroll
        for (int i = 0; i < 8; ++i) {
            int f4 = t + i * 256;
            *(float4*)&w2s[(f4 >> 5) * 128 + (f4 & 31) * 4] =
                *(const float4*)&W2[(kc * 64 + (f4 >> 5)) * U_N + u0 + (f4 & 31) * 4];
        }
        __syncthreads();
        for (int k = 0; k < 64; k += 4) {
            float4 a4 = *(const float4*)&hs[bg * 512 + kc * 64 + k];  // broadcast
            const float* ap = (const float*)&a4;
#pragma unroll
            for (int kk = 0; kk < 4; ++kk) {
                float4 w4 = *(const float4*)&w2s[(k + kk) * 128 + ug * 4];
                float av = ap[kk];
                acc[0] = fmaf(av, w4.x, acc[0]);
                acc[1] = fmaf(av, w4.y, acc[1]);
                acc[2] = fmaf(av, w4.z, acc[2]);
                acc[3] = fmaf(av, w4.w, acc[3]);
            }
        }
    }

    const int u = u0 + ug * 4;
    float4 bb1 = *(const float4*)&b1[u];
    float4 bb2 = *(const float4*)&b2[u];
    ushort o[4] = {f2bf(acc[0] + bb1.x + bb2.x), f2bf(acc[1] + bb1.y + bb2.y),
                   f2bf(acc[2] + bb1.z + bb2.z), f2bf(acc[3] + bb1.w + bb2.w)};
    *(uint2*)&ph[(size_t)(b0 + bg) * U_N + u] = *(uint2*)o;
}

// ---------------------------------------------------------------------------
// K2: per-batch fused attention with bf16 MFMA.
//  - features[b] (64x256 fp32) -> bf16, XOR-swizzled 16B chunks in LDS
//  - wave w computes proj_f tile [64 l x 128 u] via mfma_f32_16x16x32_bf16
//    (A-frags from LDS, B-frags direct from packed W1, L2-hot, coalesced)
//  - fused tanh(.+ph).V -> logit partials, shuffle+LDS reduce, wave softmax
//  - context from LDS bf16 (features read from HBM exactly once)
// LDS: 32 KB + 1.3 KB; acc = 128 VGPR/lane -> 2 blocks/CU
// ---------------------------------------------------------------------------
__global__ __launch_bounds__(256, 2) void attn_kernel(
    const float* __restrict__ features, const ushort* __restrict__ W1p,
    const float* __restrict__ V, const float* __restrict__ bV,
    const ushort* __restrict__ ph, float* __restrict__ out)
{
    __shared__ ushort As[64 * 256];   // 32 KB, chunk (m, c) at m*32 + (c ^ (m&31))
    __shared__ float lpart[4][64];
    __shared__ float wls[64];

    const int b    = blockIdx.x;
    const int t    = threadIdx.x;
    const int w    = t >> 6;
    const int lane = t & 63;
    const int ml   = lane & 15;       // m (A) / n (B) within 16-tile
    const int q    = lane >> 4;       // k-octet selector
    const float* fb = features + (size_t)b * (L_N * D_N);

    // stage features -> bf16 swizzled LDS (2048 chunks, 8/thread)
#pragma unroll
    for (int i = 0; i < 8; ++i) {
        int f = t + i * 256;
        int m = f >> 5, c = f & 31;
        float4 x0 = *(const float4*)&fb[m * D_N + c * 8];
        float4 x1 = *(const float4*)&fb[m * D_N + c * 8 + 4];
        ushort tmp[8] = {f2bf(x0.x), f2bf(x0.y), f2bf(x0.z), f2bf(x0.w),
                         f2bf(x1.x), f2bf(x1.y), f2bf(x1.z), f2bf(x1.w)};
        *(uint4*)&As[(m * 32 + (c ^ (m & 31))) * 8] = *(uint4*)tmp;
    }
    __syncthreads();

    f32x4 acc[4][8];
#pragma unroll
    for (int mt = 0; mt < 4; ++mt)
#pragma unroll
        for (int nt = 0; nt < 8; ++nt)
            acc[mt][nt] = (f32x4){0.f, 0.f, 0.f, 0.f};

    for (int ks = 0; ks < 8; ++ks) {
        bf16x8 a[4];
#pragma unroll
        for (int mt = 0; mt < 4; ++mt) {
            int m = mt * 16 + ml;
            int c = ks * 4 + q;
            a[mt] = *(const bf16x8*)&As[(m * 32 + (c ^ (m & 31))) * 8];
        }
        bf16x8 bf[8];
#pragma unroll
        for (int nt = 0; nt < 8; ++nt) {
            int chunk = ((w * 8 + nt) * 8 + ks) * 64 + lane;
            bf[nt] = *(const bf16x8*)&W1p[(size_t)chunk * 8];
        }
#pragma unroll
        for (int nt = 0; nt < 8; ++nt)
#pragma unroll
            for (int mt = 0; mt < 4; ++mt)
                acc[mt][nt] = __builtin_amdgcn_mfma_f32_16x16x32_bf16(
                    a[mt], bf[nt], acc[mt][nt], 0, 0, 0);
    }

    // epilogue: tanh(C + ph) . V -> per-lane logit partials
    // D layout: n = nt*16 + ml, m = mt*16 + q*4 + r
    float lp[16];
#pragma unroll
    for (int j = 0; j < 16; ++j) lp[j] = 0.f;
#pragma unroll
    for (int nt = 0; nt < 8; ++nt) {
        int n = w * 128 + nt * 16 + ml;
        float phv = bf2f(ph[(size_t)b * U_N + n]);
        float vv  = V[n];
#pragma unroll
        for (int mt = 0; mt < 4; ++mt)
#pragma unroll
            for (int r = 0; r < 4; ++r) {
                float s = fast_tanh(acc[mt][nt][r] + phv);
                lp[mt * 4 + r] = fmaf(s, vv, lp[mt * 4 + r]);
            }
    }
    // reduce over the 16 n-lanes (xor 1,2,4,8 stays within same q)
#pragma unroll
    for (int off = 1; off <= 8; off <<= 1)
#pragma unroll
        for (int j = 0; j < 16; ++j)
            lp[j] += __shfl_xor(lp[j], off);
    if (ml == 0) {
#pragma unroll
        for (int mt = 0; mt < 4; ++mt)
#pragma unroll
            for (int r = 0; r < 4; ++r)
                lpart[w][mt * 16 + q * 4 + r] = lp[mt * 4 + r];
    }
    __syncthreads();

    if (t < 64) {
        float lsum = bV[0] + lpart[0][t] + lpart[1][t] + lpart[2][t] + lpart[3][t];
        float mx = lsum;
#pragma unroll
        for (int off = 32; off > 0; off >>= 1)
            mx = fmaxf(mx, __shfl_xor(mx, off));
        float e = __expf(lsum - mx);
        float ssum = e;
#pragma unroll
        for (int off = 32; off > 0; off >>= 1)
            ssum += __shfl_xor(ssum, off);
        float wt = e / ssum;
        wls[t] = wt;
        out[(size_t)B_N * D_N + (size_t)b * L_N + t] = wt;  // attention_weights
    }
    __syncthreads();

    // context[d] = sum_l w_l * f[l][d], from LDS bf16 (t == d)
    float ctx = 0.f;
#pragma unroll 16
    for (int l = 0; l < L_N; ++l) {
        ushort u = As[(l * 32 + ((t >> 3) ^ (l & 31))) * 8 + (t & 7)];
        ctx = fmaf(wls[l], bf2f(u), ctx);
    }
    out[(size_t)b * D_N + t] = ctx;
}

// ---------------------------------------------------------------------------
extern "C" void kernel_launch(void* const* d_in, const int* in_sizes, int n_in,
                              void* d_out, int out_size, void* d_ws, size_t ws_size,
                              hipStream_t stream) {
    const float* features = (const float*)d_in[0];  // [2048, 64, 256]
    const float* hidden   = (const float*)d_in[1];  // [2048, 512]
    const float* W1       = (const float*)d_in[2];  // [256, 512]
    const float* b1       = (const float*)d_in[3];  // [512]
    const float* W2       = (const float*)d_in[4];  // [512, 512]
    const float* b2       = (const float*)d_in[5];  // [512]
    const float* V        = (const float*)d_in[6];  // [512, 1]
    const float* bV       = (const float*)d_in[7];  // [1]
    float* out = (float*)d_out;                     // ctx (524288) ++ attn (131072)

    // ws layout: ph bf16 [2048*512] = 2 MB @ 0; W1p bf16 256 KB @ 2 MB (2.25 MB total)
    ushort* ph  = (ushort*)d_ws;
    ushort* W1p = (ushort*)((char*)d_ws + (size_t)B_N * U_N * sizeof(ushort));

    pack_w1<<<64, 256, 0, stream>>>(W1, W1p);
    proj_h_kernel<<<dim3(B_N / 8, U_N / 128), 256, 0, stream>>>(hidden, W2, b1, b2, ph);
    attn_kernel<<<B_N, 256, 0, stream>>>(features, W1p, V, bV, ph, out);
}